// Round 1
// baseline (236.421 us; speedup 1.0000x reference)
//
#include <hip/hip_runtime.h>

#define DECAY 0.25f

__global__ __launch_bounds__(256) void lif_mem_update_kernel(
    const float* __restrict__ x, float* __restrict__ out, long long n4)
{
    const float4* __restrict__ x4 = (const float4*)x;
    float4* __restrict__ o4 = (float4*)out;

    long long stride = (long long)gridDim.x * blockDim.x;
    for (long long i = (long long)blockIdx.x * blockDim.x + threadIdx.x;
         i < n4; i += stride)
    {
        float4 mem = make_float4(0.f, 0.f, 0.f, 0.f);
        float4 spk = make_float4(0.f, 0.f, 0.f, 0.f);
        #pragma unroll
        for (int t = 0; t < 4; ++t) {
            float4 xi = x4[(long long)t * n4 + i];

            mem.x = (mem.x - spk.x * 0.5f) * DECAY + xi.x;
            mem.y = (mem.y - spk.y * 0.5f) * DECAY + xi.y;
            mem.z = (mem.z - spk.z * 0.5f) * DECAY + xi.z;
            mem.w = (mem.w - spk.w * 0.5f) * DECAY + xi.w;

            // s = round(clip(mem, 0, 1)); jnp.round = half-to-even = rintf
            float4 s;
            s.x = rintf(fminf(fmaxf(mem.x, 0.f), 1.f));
            s.y = rintf(fminf(fmaxf(mem.y, 0.f), 1.f));
            s.z = rintf(fminf(fmaxf(mem.z, 0.f), 1.f));
            s.w = rintf(fminf(fmaxf(mem.w, 0.f), 1.f));

            o4[(long long)t * n4 + i] = s;
            spk = s;
        }
    }
}

extern "C" void kernel_launch(void* const* d_in, const int* in_sizes, int n_in,
                              void* d_out, int out_size, void* d_ws, size_t ws_size,
                              hipStream_t stream)
{
    const float* x = (const float*)d_in[0];
    float* out = (float*)d_out;

    // x: [T=4, B*C*H*W = 8388608] floats. Plane size N = total/4.
    long long total = (long long)in_sizes[0];   // 33554432
    long long nplane = total / 4;               // 8388608
    long long n4 = nplane / 4;                  // 2097152 float4 per plane

    const int block = 256;
    int grid = 2048; // grid-stride; 256 CUs * 8 blocks/CU
    long long needed = (n4 + block - 1) / block;
    if (needed < grid) grid = (int)needed;

    lif_mem_update_kernel<<<grid, block, 0, stream>>>(x, out, n4);
}

// Round 7
// 233.776 us; speedup vs baseline: 1.0113x; 1.0113x over previous
//
#include <hip/hip_runtime.h>

#define DECAY 0.25f

typedef float fx4 __attribute__((ext_vector_type(4)));

__device__ __forceinline__ fx4 step4(fx4 mem, fx4 spk, fx4 xi, fx4* s_out)
{
    fx4 m = (mem - spk * 0.5f) * DECAY + xi;
    fx4 s;
    s.x = rintf(fminf(fmaxf(m.x, 0.f), 1.f));
    s.y = rintf(fminf(fmaxf(m.y, 0.f), 1.f));
    s.z = rintf(fminf(fmaxf(m.z, 0.f), 1.f));
    s.w = rintf(fminf(fmaxf(m.w, 0.f), 1.f));
    *s_out = s;
    return m;
}

__global__ __launch_bounds__(256) void lif_mem_update_kernel(
    const float* __restrict__ x, float* __restrict__ out, long long n4)
{
    const fx4* __restrict__ x4 = (const fx4*)x;
    fx4* __restrict__ o4 = (fx4*)out;

    long long i = (long long)blockIdx.x * blockDim.x + threadIdx.x;
    if (i >= n4) return;

    // Issue all 4 plane loads up front — independent, max MLP.
    fx4 x0 = x4[i];
    fx4 x1 = x4[i + n4];
    fx4 x2 = x4[i + 2 * n4];
    fx4 x3 = x4[i + 3 * n4];

    fx4 zero = (fx4)(0.f);
    fx4 s0, s1, s2, s3;
    fx4 m;
    m = step4(zero, zero, x0, &s0);
    m = step4(m,    s0,   x1, &s1);
    m = step4(m,    s1,   x2, &s2);
    m = step4(m,    s2,   x3, &s3);

    // Output is streamed, never re-read this launch: non-temporal stores
    // keep x's footprint resident in L2/L3 (preserves the read absorption).
    __builtin_nontemporal_store(s0, &o4[i]);
    __builtin_nontemporal_store(s1, &o4[i + n4]);
    __builtin_nontemporal_store(s2, &o4[i + 2 * n4]);
    __builtin_nontemporal_store(s3, &o4[i + 3 * n4]);
}

extern "C" void kernel_launch(void* const* d_in, const int* in_sizes, int n_in,
                              void* d_out, int out_size, void* d_ws, size_t ws_size,
                              hipStream_t stream)
{
    const float* x = (const float*)d_in[0];
    float* out = (float*)d_out;

    long long total = (long long)in_sizes[0];   // 33554432 floats = [4][8388608]
    long long nplane = total / 4;               // 8388608 floats per plane
    long long n4 = nplane / 4;                  // 2097152 float4 per plane

    const int block = 256;
    long long grid = (n4 + block - 1) / block;  // 8192 blocks, one float4 per thread
    lif_mem_update_kernel<<<(int)grid, block, 0, stream>>>(x, out, n4);
}